// Round 1
// baseline (7328.743 us; speedup 1.0000x reference)
//
#include <hip/hip_runtime.h>

#define NVOX 128
#define LO   (-200.0f)
#define VPIX (3.125f)          // 400/128
#define INV_V (0.32f)          // 1/3.125 exact
// kw^2 = 9/pi ; -0.5/kw^2 = -pi/18
#define NEG_HALF_INV_KW2 (-0.17453292519943295f)

// DIR: 0 = xlors -> out[iy][iz][k], 1 = ylors -> out[iy][k][iz], 2 = zlors -> out[k][iy][iz]
template<int DIR>
__global__ __launch_bounds__(256) void bp_kernel(
    const float* __restrict__ lors,   // (6, nlor) row-major
    const float* __restrict__ proj,   // (nlor,)
    float* __restrict__ out,          // 128^3 f32
    int nlor)
{
    int tid = blockIdx.x * 256 + threadIdx.x;
    int k = tid & (NVOX - 1);     // slice index, inner -> 128 threads share one LOR
    int n = tid >> 7;             // LOR index
    if (n >= nlor) return;

    // broadcast loads (same n across 128 threads)
    float p1x = lors[0 * nlor + n];
    float p1y = lors[1 * nlor + n];
    float p1z = lors[2 * nlor + n];
    float p2x = lors[3 * nlor + n];
    float p2y = lors[4 * nlor + n];
    float p2z = lors[5 * nlor + n];
    float pr  = proj[n];

    float xk = LO + (k + 0.5f) * VPIX;
    float t  = (xk - p1x) / (p2x - p1x);
    if (t < 0.0f || t > 1.0f) return;   // reference masks these to zero weight

    float y = p1y + t * (p2y - p1y);
    float z = p1z + t * (p2z - p1z);

    float fy = (y - LO) * INV_V - 0.5f;
    float fz = (z - LO) * INV_V - 0.5f;
    int iy0 = (int)floorf(fy) - 1;
    int iz0 = (int)floorf(fz) - 1;

    // separable Gaussian weights; fold proj into wy
    float wy[3], wz[3];
    #pragma unroll
    for (int o = 0; o < 3; ++o) {
        int iy = iy0 + o;
        float cy = LO + (iy + 0.5f) * VPIX;
        float dy = cy - y;
        wy[o] = (iy >= 0 && iy < NVOX) ? __expf(NEG_HALF_INV_KW2 * dy * dy) * pr : 0.0f;

        int iz = iz0 + o;
        float cz = LO + (iz + 0.5f) * VPIX;
        float dz = cz - z;
        wz[o] = (iz >= 0 && iz < NVOX) ? __expf(NEG_HALF_INV_KW2 * dz * dz) : 0.0f;
    }

    #pragma unroll
    for (int oy = 0; oy < 3; ++oy) {
        if (wy[oy] == 0.0f) continue;
        int iy = iy0 + oy;
        #pragma unroll
        for (int oz = 0; oz < 3; ++oz) {
            if (wz[oz] == 0.0f) continue;
            int iz = iz0 + oz;
            float w = wy[oy] * wz[oz];
            int idx;
            if (DIR == 0)      idx = (iy * NVOX + iz) * NVOX + k;
            else if (DIR == 1) idx = (iy * NVOX + k) * NVOX + iz;
            else               idx = (k * NVOX + iy) * NVOX + iz;
            atomicAdd(&out[idx], w);
        }
    }
}

extern "C" void kernel_launch(void* const* d_in, const int* in_sizes, int n_in,
                              void* d_out, int out_size, void* d_ws, size_t ws_size,
                              hipStream_t stream) {
    // setup_inputs order: image, grid, center, size, xlors, ylors, zlors, xproj, yproj, zproj
    const float* xlors = (const float*)d_in[4];
    const float* ylors = (const float*)d_in[5];
    const float* zlors = (const float*)d_in[6];
    const float* xproj = (const float*)d_in[7];
    const float* yproj = (const float*)d_in[8];
    const float* zproj = (const float*)d_in[9];
    float* out = (float*)d_out;
    const int nlor = in_sizes[7];   // 50000

    hipMemsetAsync(d_out, 0, (size_t)out_size * sizeof(float), stream);

    const int total  = nlor * NVOX;
    const int blocks = (total + 255) / 256;
    bp_kernel<0><<<blocks, 256, 0, stream>>>(xlors, xproj, out, nlor);
    bp_kernel<1><<<blocks, 256, 0, stream>>>(ylors, yproj, out, nlor);
    bp_kernel<2><<<blocks, 256, 0, stream>>>(zlors, zproj, out, nlor);
}

// Round 2
// 5010.371 us; speedup vs baseline: 1.4627x; 1.4627x over previous
//
#include <hip/hip_runtime.h>

#define NVOX 128
#define VOL  (NVOX * NVOX * NVOX)
#define LO   (-200.0f)
#define VPIX (3.125f)           // 400/128
#define INV_V (0.32f)           // 1/3.125 exact
// kw^2 = 9/pi ; -0.5/kw^2 = -pi/18
#define NEG_HALF_INV_KW2 (-0.17453292519943295f)

// Deposit into vol[iy][iz][k] — k (lane-varying) innermost so a wave's
// atomics hit ~4 cache lines per instruction instead of 64.
__global__ __launch_bounds__(256) void bp_natural(
    const float* __restrict__ lors,   // (6, nlor) row-major
    const float* __restrict__ proj,   // (nlor,)
    float* __restrict__ vol,          // 128^3 f32, layout [iy][iz][k]
    int nlor)
{
    int tid = blockIdx.x * 256 + threadIdx.x;
    int k = tid & (NVOX - 1);
    int n = tid >> 7;
    if (n >= nlor) return;

    float p1x = lors[0 * nlor + n];
    float p1y = lors[1 * nlor + n];
    float p1z = lors[2 * nlor + n];
    float p2x = lors[3 * nlor + n];
    float p2y = lors[4 * nlor + n];
    float p2z = lors[5 * nlor + n];
    float pr  = proj[n];

    float xk = LO + (k + 0.5f) * VPIX;
    float t  = (xk - p1x) / (p2x - p1x);
    if (t < 0.0f || t > 1.0f) return;

    float y = p1y + t * (p2y - p1y);
    float z = p1z + t * (p2z - p1z);

    float fy = (y - LO) * INV_V - 0.5f;
    float fz = (z - LO) * INV_V - 0.5f;
    int iy0 = (int)floorf(fy) - 1;
    int iz0 = (int)floorf(fz) - 1;

    float wy[3], wz[3];
    #pragma unroll
    for (int o = 0; o < 3; ++o) {
        int iy = iy0 + o;
        float cy = LO + (iy + 0.5f) * VPIX;
        float dy = cy - y;
        wy[o] = (iy >= 0 && iy < NVOX) ? __expf(NEG_HALF_INV_KW2 * dy * dy) * pr : 0.0f;

        int iz = iz0 + o;
        float cz = LO + (iz + 0.5f) * VPIX;
        float dz = cz - z;
        wz[o] = (iz >= 0 && iz < NVOX) ? __expf(NEG_HALF_INV_KW2 * dz * dz) : 0.0f;
    }

    #pragma unroll
    for (int oy = 0; oy < 3; ++oy) {
        if (wy[oy] == 0.0f) continue;
        int iy = iy0 + oy;
        #pragma unroll
        for (int oz = 0; oz < 3; ++oz) {
            if (wz[oz] == 0.0f) continue;
            int iz = iz0 + oz;
            atomicAdd(&vol[(iy * NVOX + iz) * NVOX + k], wy[oy] * wz[oz]);
        }
    }
}

// Fallback (round-1 style) direct-to-out scatter for DIR=1 (y) and DIR=2 (z),
// used only if d_ws is too small for two scratch volumes.
template<int DIR>
__global__ __launch_bounds__(256) void bp_direct(
    const float* __restrict__ lors, const float* __restrict__ proj,
    float* __restrict__ out, int nlor)
{
    int tid = blockIdx.x * 256 + threadIdx.x;
    int k = tid & (NVOX - 1);
    int n = tid >> 7;
    if (n >= nlor) return;

    float p1x = lors[0 * nlor + n];
    float p1y = lors[1 * nlor + n];
    float p1z = lors[2 * nlor + n];
    float p2x = lors[3 * nlor + n];
    float p2y = lors[4 * nlor + n];
    float p2z = lors[5 * nlor + n];
    float pr  = proj[n];

    float xk = LO + (k + 0.5f) * VPIX;
    float t  = (xk - p1x) / (p2x - p1x);
    if (t < 0.0f || t > 1.0f) return;

    float y = p1y + t * (p2y - p1y);
    float z = p1z + t * (p2z - p1z);

    float fy = (y - LO) * INV_V - 0.5f;
    float fz = (z - LO) * INV_V - 0.5f;
    int iy0 = (int)floorf(fy) - 1;
    int iz0 = (int)floorf(fz) - 1;

    float wy[3], wz[3];
    #pragma unroll
    for (int o = 0; o < 3; ++o) {
        int iy = iy0 + o;
        float cy = LO + (iy + 0.5f) * VPIX;
        float dy = cy - y;
        wy[o] = (iy >= 0 && iy < NVOX) ? __expf(NEG_HALF_INV_KW2 * dy * dy) * pr : 0.0f;
        int iz = iz0 + o;
        float cz = LO + (iz + 0.5f) * VPIX;
        float dz = cz - z;
        wz[o] = (iz >= 0 && iz < NVOX) ? __expf(NEG_HALF_INV_KW2 * dz * dz) : 0.0f;
    }

    #pragma unroll
    for (int oy = 0; oy < 3; ++oy) {
        if (wy[oy] == 0.0f) continue;
        int iy = iy0 + oy;
        #pragma unroll
        for (int oz = 0; oz < 3; ++oz) {
            if (wz[oz] == 0.0f) continue;
            int iz = iz0 + oz;
            int idx = (DIR == 1) ? (iy * NVOX + k) * NVOX + iz
                                 : (k * NVOX + iy) * NVOX + iz;
            atomicAdd(&out[idx], wy[oy] * wz[oz]);
        }
    }
}

// out[a][b][c] += Sy[a][c][b] + Sz[b][c][a]
// (x-direction accumulated directly into out; Sy/Sz are 8 MB, L2/LLC-resident)
__global__ __launch_bounds__(128) void merge_kernel(
    float* __restrict__ out,
    const float* __restrict__ Sy,
    const float* __restrict__ Sz)
{
    int c = threadIdx.x;
    int b = blockIdx.x;
    int a = blockIdx.y;
    out[(a * NVOX + b) * NVOX + c] +=
        Sy[(a * NVOX + c) * NVOX + b] + Sz[(b * NVOX + c) * NVOX + a];
}

extern "C" void kernel_launch(void* const* d_in, const int* in_sizes, int n_in,
                              void* d_out, int out_size, void* d_ws, size_t ws_size,
                              hipStream_t stream) {
    const float* xlors = (const float*)d_in[4];
    const float* ylors = (const float*)d_in[5];
    const float* zlors = (const float*)d_in[6];
    const float* xproj = (const float*)d_in[7];
    const float* yproj = (const float*)d_in[8];
    const float* zproj = (const float*)d_in[9];
    float* out = (float*)d_out;
    const int nlor = in_sizes[7];

    const int total  = nlor * NVOX;
    const int blocks = (total + 255) / 256;

    hipMemsetAsync(d_out, 0, (size_t)VOL * sizeof(float), stream);

    if (ws_size >= 2 * (size_t)VOL * sizeof(float)) {
        float* Sy = (float*)d_ws;
        float* Sz = Sy + VOL;
        hipMemsetAsync(d_ws, 0, 2 * (size_t)VOL * sizeof(float), stream);

        // x-direction's natural layout [iy][iz][k] IS the output layout
        bp_natural<<<blocks, 256, 0, stream>>>(xlors, xproj, out, nlor);
        bp_natural<<<blocks, 256, 0, stream>>>(ylors, yproj, Sy, nlor);
        bp_natural<<<blocks, 256, 0, stream>>>(zlors, zproj, Sz, nlor);

        dim3 mgrid(NVOX, NVOX);
        merge_kernel<<<mgrid, NVOX, 0, stream>>>(out, Sy, Sz);
    } else {
        bp_natural<<<blocks, 256, 0, stream>>>(xlors, xproj, out, nlor);
        bp_direct<1><<<blocks, 256, 0, stream>>>(ylors, yproj, out, nlor);
        bp_direct<2><<<blocks, 256, 0, stream>>>(zlors, zproj, out, nlor);
    }
}